// Round 2
// baseline (4833.181 us; speedup 1.0000x reference)
//
#include <hip/hip_runtime.h>
#include <hip/hip_bf16.h>

#define Tc 100
#define Hc 512
#define Lc 3
#define H3c 1536
#define HLAY (512*512)          // elems per layer slice of an hb slot
#define HSLOT (Lc*512*512)      // elems per hb parity slot

typedef short bf16x8 __attribute__((ext_vector_type(8)));
typedef float f32x4 __attribute__((ext_vector_type(4)));

__device__ __forceinline__ unsigned short f2bf(float f) {
  unsigned int u = __float_as_uint(f);
  u += 0x7FFFu + ((u >> 16) & 1u);   // round-to-nearest-even
  return (unsigned short)(u >> 16);
}

__global__ __launch_bounds__(256) void conv_bf16(const float* __restrict__ src,
                                                 unsigned short* __restrict__ dst,
                                                 int n4) {
  int i = blockIdx.x * 256 + threadIdx.x;
  if (i >= n4) return;
  f32x4 v = *(const f32x4*)(src + (size_t)i * 4);
  ushort4 o;
  o.x = f2bf(v[0]); o.y = f2bf(v[1]); o.z = f2bf(v[2]); o.w = f2bf(v[3]);
  *(ushort4*)(dst + (size_t)i * 4) = o;
}

__device__ __forceinline__ void spinwait(int* p, int tgt) {
  int it = 0;
  while (__hip_atomic_load(p, __ATOMIC_ACQUIRE, __HIP_MEMORY_SCOPE_AGENT) < tgt) {
    __builtin_amdgcn_s_sleep(8);
    if (++it > 4000000) break;   // safety: turn a deadlock bug into fast-fail
  }
}

#define GLOAD_LDS16(g, l)                                                        \
  __builtin_amdgcn_global_load_lds(                                              \
      (const __attribute__((address_space(1))) void*)(g),                        \
      (__attribute__((address_space(3))) void*)(l), 16, 0, 0)

// Persistent dataflow GRU. 192 blocks x 256 threads (1 block/CU, all co-resident).
// Block owns (layer l, rowblock rb of 128 rows, colblock cb of 32 cols) for all t.
// W (6 gate-mats x 32 cols) staged to LDS per 64-k chunk, double-buffered,
// XOR-swizzled (rows 128B, byte ^= (row&7)<<4) via pre-swizzled global source.
// A operands (h rows) direct-loaded; h_prev fp32 kept in registers across steps.
// Sync: cnt[l][t][rb] produce-flags (target 16), rd[l][t][rb] read-flags for WAR
// on the parity-2 bf16 h ring.
__global__ __launch_bounds__(256, 1) void gru_persist(
    const float* __restrict__ x,     // [B,T,A,H] f32
    const short* __restrict__ wbih,  // [L,3H,H] bf16
    const short* __restrict__ wbhh,  // [L,3H,H] bf16
    const float* __restrict__ bih,   // [L,3H]
    const float* __restrict__ bhh,   // [L,3H]
    short* hb,                       // [2][L][512][512] bf16 parity ring
    const int* __restrict__ valid,   // [B,T,A] int32
    float* __restrict__ y,           // [B,T,A,H] f32
    int* cnt,                        // [L][T][4]
    int* rd) {                       // [L][T+2][4]
  __shared__ char wlds[2][24576];    // 2 x (192 rows x 128B)

  int bid = blockIdx.x;
  // XCD co-location: blocks sharing (l,cb) weights land on the same XCD (bid%8).
  int x8 = bid & 7, gq = bid >> 3;
  int grp = gq % 6, rb = gq / 6;
  int idx = grp * 8 + x8;
  int l = idx >> 4, cb = idx & 15;
  int c0 = cb * 32;
  int R0 = rb * 128;

  int tid = threadIdx.x;
  int w = tid >> 6, lane = tid & 63;
  int lrow = lane & 15, kgrp = lane >> 4;
  int swz = (lrow & 7) << 4;

  const short* wih_l = wbih + (size_t)l * H3c * Hc;
  const short* whh_l = wbhh + (size_t)l * H3c * Hc;
  const float* bihl = bih + l * H3c;
  const float* bhhl = bhh + l * H3c;

  // biases for this thread's two col-fragments (col fixed across all t)
  float bi_[3][2], bh_[3][2];
#pragma unroll
  for (int g3 = 0; g3 < 3; ++g3)
#pragma unroll
    for (int cf = 0; cf < 2; ++cf) {
      int c = c0 + cf * 16 + lrow;
      bi_[g3][cf] = bihl[g3 * 512 + c];
      bh_[g3][cf] = bhhl[g3 * 512 + c];
    }

  int arow0 = R0 + w * 32 + lrow;   // A-fragment rows (rf=0), rf=1 at +16

  f32x4 hreg[2][2];                 // fp32 h_prev for this thread's 16 outputs
#pragma unroll
  for (int rf = 0; rf < 2; ++rf)
#pragma unroll
    for (int cf = 0; cf < 2; ++cf) hreg[rf][cf] = f32x4{0.f, 0.f, 0.f, 0.f};

  for (int t = 0; t < Tc; ++t) {
    if (tid == 0) {
      if (l > 0) spinwait(&cnt[((l - 1) * Tc + t) * 4 + rb], 16);
      if (t > 0) spinwait(&cnt[(l * Tc + (t - 1)) * 4 + rb], 16);
    }
    __syncthreads();

    int par = t & 1;
    const short* hprev = hb + (size_t)(1 - par) * HSLOT + (size_t)l * HLAY;
    const short* ain = hb + (size_t)par * HSLOT + (size_t)(l - 1) * HLAY; // l>0 only

    f32x4 acci[3][2][2], acch[3][2][2];
#pragma unroll
    for (int g3 = 0; g3 < 3; ++g3)
#pragma unroll
      for (int rf = 0; rf < 2; ++rf)
#pragma unroll
        for (int cf = 0; cf < 2; ++cf) {
          acci[g3][rf][cf] = f32x4{0.f, 0.f, 0.f, 0.f};
          acch[g3][rf][cf] = f32x4{0.f, 0.f, 0.f, 0.f};
        }

    // --- W staging: 24 x 1KB instrs per chunk, 6 per wave. LDS row rr (128B):
    // rr<96 -> W_ih[gate=rr/32][col=c0+rr%32], rr>=96 -> W_hh. Source byte
    // pre-swizzled so read-side XOR lands on linear data.
#define STAGE_W(ckn, buf)                                                          \
    {                                                                              \
      int k0 = (ckn) * 64;                                                         \
      _Pragma("unroll") for (int i = 0; i < 6; ++i) {                              \
        int j = w * 6 + i;                                                         \
        int ldsb = j * 1024 + lane * 16;                                           \
        int rr = ldsb >> 7;                                                        \
        int off = ldsb & 127;                                                      \
        int soff = off ^ ((rr & 7) << 4);                                          \
        int mat = rr >= 96;                                                        \
        int rm = mat ? rr - 96 : rr;                                               \
        int n = ((rm >> 5) << 9) + c0 + (rm & 31);                                 \
        const short* base = (mat ? whh_l : wih_l) + (size_t)n * 512 + k0;          \
        GLOAD_LDS16((const char*)base + soff, &wlds[buf][j * 1024]);               \
      }                                                                            \
    }

    STAGE_W(0, 0);
    __syncthreads();

    for (int ck = 0; ck < 8; ++ck) {
      if (ck < 7) STAGE_W(ck + 1, (ck + 1) & 1);
      const char* wbuf = wlds[ck & 1];

      // A fragments (direct global, wave-private rows)
      bf16x8 Ai[2][2], Ah[2][2];
#pragma unroll
      for (int rf = 0; rf < 2; ++rf) {
        int arow = arow0 + rf * 16;
#pragma unroll
        for (int ks = 0; ks < 2; ++ks) {
          int k = ck * 64 + ks * 32 + kgrp * 8;
          Ah[rf][ks] = *(const bf16x8*)(hprev + (size_t)arow * 512 + k);
          if (l > 0) {
            Ai[rf][ks] = *(const bf16x8*)(ain + (size_t)arow * 512 + k);
          } else {
            const float* px = x + ((size_t)((arow >> 6) * Tc + t) * 64 + (arow & 63)) * 512 + k;
            f32x4 v0 = *(const f32x4*)px;
            f32x4 v1 = *(const f32x4*)(px + 4);
            bf16x8 tmp;
#pragma unroll
            for (int e = 0; e < 4; ++e) {
              tmp[e] = (short)f2bf(v0[e]);
              tmp[4 + e] = (short)f2bf(v1[e]);
            }
            Ai[rf][ks] = tmp;
          }
        }
      }

#pragma unroll
      for (int ks = 0; ks < 2; ++ks)
#pragma unroll
        for (int g3 = 0; g3 < 3; ++g3)
#pragma unroll
          for (int cf = 0; cf < 2; ++cf) {
            int rri = g3 * 32 + cf * 16 + lrow;
            int byi = rri * 128 + ((ks * 64 + kgrp * 16) ^ swz);
            bf16x8 bi = *(const bf16x8*)(wbuf + byi);
            bf16x8 bh = *(const bf16x8*)(wbuf + byi + 96 * 128);
#pragma unroll
            for (int rf = 0; rf < 2; ++rf) {
              acci[g3][rf][cf] = __builtin_amdgcn_mfma_f32_16x16x32_bf16(Ai[rf][ks], bi, acci[g3][rf][cf], 0, 0, 0);
              acch[g3][rf][cf] = __builtin_amdgcn_mfma_f32_16x16x32_bf16(Ah[rf][ks], bh, acch[g3][rf][cf], 0, 0, 0);
            }
          }
      __syncthreads();
    }

    // publish read-completion; WAR wait before overwriting slot `par` (content t-2)
    if (tid == 0) {
      __hip_atomic_fetch_add(&rd[(l * (Tc + 2) + (t + 1)) * 4 + rb], 1,
                             __ATOMIC_RELEASE, __HIP_MEMORY_SCOPE_AGENT);
      if (l > 0)
        __hip_atomic_fetch_add(&rd[((l - 1) * (Tc + 2) + (t + 2)) * 4 + rb], 1,
                               __ATOMIC_RELEASE, __HIP_MEMORY_SCOPE_AGENT);
      int wtgt = (t == 0) ? 0 : (t == 1 ? 16 : (l < 2 ? 32 : 16));
      if (wtgt) spinwait(&rd[(l * (Tc + 2) + t) * 4 + rb], wtgt);
    }
    __syncthreads();

    // epilogue: C/D map col=lane&15, row=(lane>>4)*4+reg (m89-verified)
    short* hout = hb + (size_t)par * HSLOT + (size_t)l * HLAY;
#pragma unroll
    for (int rf = 0; rf < 2; ++rf)
#pragma unroll
      for (int rr = 0; rr < 4; ++rr) {
        int mloc = w * 32 + rf * 16 + kgrp * 4 + rr;
        int rowg = R0 + mloc;
        int vofs = ((rowg >> 6) * Tc + t) * 64 + (rowg & 63);
        int vld = valid[vofs];
#pragma unroll
        for (int cf = 0; cf < 2; ++cf) {
          int c = c0 + cf * 16 + lrow;
          float ir = acci[0][rf][cf][rr] + bi_[0][cf];
          float iz = acci[1][rf][cf][rr] + bi_[1][cf];
          float in_ = acci[2][rf][cf][rr] + bi_[2][cf];
          float hr = acch[0][rf][cf][rr] + bh_[0][cf];
          float hz = acch[1][rf][cf][rr] + bh_[1][cf];
          float hn = acch[2][rf][cf][rr] + bh_[2][cf];
          float rg = 1.0f / (1.0f + __expf(-(ir + hr)));
          float zg = 1.0f / (1.0f + __expf(-(iz + hz)));
          float ng = tanhf(in_ + rg * hn);
          float hp = hreg[rf][cf][rr];
          float hnew = (1.0f - zg) * ng + zg * hp;
          if (!vld) hnew = 0.0f;
          hreg[rf][cf][rr] = hnew;
          hout[(size_t)rowg * 512 + c] = (short)f2bf(hnew);
          if (l == 2) y[(size_t)vofs * 512 + c] = hnew;
        }
      }
    __syncthreads();   // all stores drained (vmcnt) before release
    if (tid == 0)
      __hip_atomic_fetch_add(&cnt[(l * Tc + t) * 4 + rb], 1,
                             __ATOMIC_RELEASE, __HIP_MEMORY_SCOPE_AGENT);
#undef STAGE_W
  }
}

extern "C" void kernel_launch(void* const* d_in, const int* in_sizes, int n_in,
                              void* d_out, int out_size, void* d_ws, size_t ws_size,
                              hipStream_t stream) {
  const float* x = (const float*)d_in[0];
  const int* valid = (const int*)d_in[1];
  const float* w_ih = (const float*)d_in[2];
  const float* w_hh = (const float*)d_in[3];
  const float* b_ih = (const float*)d_in[4];
  const float* b_hh = (const float*)d_in[5];
  float* y = (float*)d_out;

  char* ws = (char*)d_ws;
  const size_t welems = (size_t)Lc * H3c * Hc;            // 2,359,296
  unsigned short* wbih = (unsigned short*)ws;             // 4.5 MB
  unsigned short* wbhh = (unsigned short*)(ws + welems * 2);
  short* hb = (short*)(ws + welems * 4);                  // [2][L][512][512] bf16: 3.1 MB
  size_t hb_bytes = (size_t)2 * HSLOT * 2;
  int* cnt = (int*)(ws + welems * 4 + hb_bytes);          // [3][100][4]
  int* rd = cnt + Lc * Tc * 4;                            // [3][102][4]

  int n4 = (int)(welems / 4);
  conv_bf16<<<(n4 + 255) / 256, 256, 0, stream>>>(w_ih, wbih, n4);
  conv_bf16<<<(n4 + 255) / 256, 256, 0, stream>>>(w_hh, wbhh, n4);
  (void)hipMemsetAsync(hb, 0, hb_bytes, stream);
  (void)hipMemsetAsync(cnt, 0, (size_t)(Lc * Tc * 4 + Lc * (Tc + 2) * 4) * sizeof(int), stream);

  gru_persist<<<192, 256, 0, stream>>>(x, (const short*)wbih, (const short*)wbhh,
                                       b_ih, b_hh, hb, valid, y, cnt, rd);
}

// Round 3
// 3945.491 us; speedup vs baseline: 1.2250x; 1.2250x over previous
//
#include <hip/hip_runtime.h>

#define Tc 100
#define Hc 512
#define Lc 3
#define H3c 1536
#define HLAY (Hc*Hc)            // 262144 elems per layer slice of an hb slot
#define HSLOT (Lc*HLAY)         // elems per hb parity slot

typedef short bf16x8 __attribute__((ext_vector_type(8)));
typedef float f32x4 __attribute__((ext_vector_type(4)));

__device__ __forceinline__ unsigned short f2bf(float f) {
  unsigned int u = __float_as_uint(f);
  u += 0x7FFFu + ((u >> 16) & 1u);   // round-to-nearest-even
  return (unsigned short)(u >> 16);
}

__global__ __launch_bounds__(256) void conv_bf16(const float* __restrict__ src,
                                                 unsigned short* __restrict__ dst,
                                                 int n4) {
  int i = blockIdx.x * 256 + threadIdx.x;
  if (i >= n4) return;
  f32x4 v = *(const f32x4*)(src + (size_t)i * 4);
  ushort4 o;
  o.x = f2bf(v[0]); o.y = f2bf(v[1]); o.z = f2bf(v[2]); o.w = f2bf(v[3]);
  *(ushort4*)(dst + (size_t)i * 4) = o;
}

// Relaxed spin (no L2-invalidate per poll), then ONE acquire load as the fence.
__device__ __forceinline__ void spin_acq(int* p, int tgt) {
  int it = 0;
  while (__hip_atomic_load(p, __ATOMIC_RELAXED, __HIP_MEMORY_SCOPE_AGENT) < tgt) {
    __builtin_amdgcn_s_sleep(2);
    if (++it > 6000000) break;      // deadlock -> fast wrong answer, not hang
  }
  while (__hip_atomic_load(p, __ATOMIC_ACQUIRE, __HIP_MEMORY_SCOPE_AGENT) < tgt) {
    __builtin_amdgcn_s_sleep(2);
    if (++it > 6100000) break;
  }
}

// Persistent dataflow GRU, weights LDS-resident.
// 192 blocks x 256 thr. Block = (l, rb: 256 rows, cb: 16 cols) for all t.
// LDS: [96 rows][1024 B] = {gi_r,gi_z,gi_n,gh_r,gh_z,gh_n} x 16 cols x 512 K bf16,
// XOR-swizzled (byte ^= (row&7)<<4) -> conflict-free ds_read_b128. Filled ONCE.
// K-loop has no barriers (LDS read-only, A wave-private). 2 syncthreads/stage.
// Flags: cnt[l][t][rb] (target 32 = cb-blocks) RAW; rd[l][t][rb] WAR on parity ring.
__global__ __launch_bounds__(256, 1) void gru_persist2(
    const float* __restrict__ x,     // [B,T,A,H] f32 (fallback path)
    const short* __restrict__ xb,    // [B,T,A,H] bf16 or nullptr
    const short* __restrict__ wbih,  // [L,3H,H] bf16
    const short* __restrict__ wbhh,  // [L,3H,H] bf16
    const float* __restrict__ bih,   // [L,3H]
    const float* __restrict__ bhh,   // [L,3H]
    short* hb,                       // [2][L][512][512] bf16 parity ring
    const int* __restrict__ valid,   // [B,T,A] int32
    float* __restrict__ y,           // [B,T,A,H] f32
    int* cnt, int* rd) {
  __shared__ char wlds[98304];

  const int bid = blockIdx.x;
  const int xcd = bid & 7;
  const int q = bid >> 3;            // 0..23
  const int l = q % 3;
  const int u = q / 3;               // 0..7
  const int rb = u & 1;
  const int cb = (u >> 1) * 8 + xcd; // 0..31
  const int c0 = cb * 16;
  const int R0 = rb * 256;

  const int tid = threadIdx.x;
  const int w = tid >> 6;
  const int lane = tid & 63;
  const int lrow = lane & 15;
  const int kgrp = lane >> 4;

  const short* wih_l = wbih + (size_t)l * H3c * Hc;
  const short* whh_l = wbhh + (size_t)l * H3c * Hc;

  // ---- one-time LDS weight fill (stored pre-swizzled) ----
#pragma unroll
  for (int it = 0; it < 24; ++it) {
    int idx = it * 256 + tid;        // 96 rows x 64 16B-slots
    int r = idx >> 6;
    int off16 = (idx & 63) << 4;
    int soff = off16 ^ ((r & 7) << 4);
    int mat = r >> 4;                // 0-2 gi gates, 3-5 gh gates
    int g = (mat < 3) ? mat : (mat - 3);
    int n = g * Hc + c0 + (r & 15);
    const short* base = ((mat < 3) ? wih_l : whh_l) + (size_t)n * Hc;
    *(bf16x8*)(wlds + r * 1024 + off16) = *(const bf16x8*)((const char*)base + soff);
  }
  __syncthreads();

  const float* bihl = bih + l * H3c;
  const float* bhhl = bhh + l * H3c;
  const int c = c0 + lrow;           // this lane's output column
  const float bi0 = bihl[c], bi1 = bihl[Hc + c], bi2 = bihl[2 * Hc + c];
  const float bh0 = bhhl[c], bh1 = bhhl[Hc + c], bh2 = bhhl[2 * Hc + c];

  f32x4 hreg[4];                     // fp32 h_prev, 16 outputs/lane
#pragma unroll
  for (int rf = 0; rf < 4; ++rf) hreg[rf] = f32x4{0.f, 0.f, 0.f, 0.f};

  const int swzB = (lrow & 7) << 4;

  for (int t = 0; t < Tc; ++t) {
    if (tid == 0) {
      if (l > 0) spin_acq(&cnt[((l - 1) * Tc + t) * 2 + rb], 32);
      if (t > 0) spin_acq(&cnt[(l * Tc + (t - 1)) * 2 + rb], 32);
      if (t >= 2) spin_acq(&rd[(l * Tc + (t - 2)) * 2 + rb], 32 + (l < 2 ? 32 : 0));
    }
    __syncthreads();                 // flag + acquire-inv ordered before all reads

    const int par = t & 1;
    const short* hprev = hb + (size_t)(1 - par) * HSLOT + (size_t)l * HLAY;

    const short* pH[4];
    const short* pA[4];
    const float* pXf[4];
#pragma unroll
    for (int rf = 0; rf < 4; ++rf) {
      int row = R0 + w * 64 + rf * 16 + lrow;
      pH[rf] = hprev + (size_t)row * Hc;
      if (l > 0) {
        pA[rf] = hb + (size_t)par * HSLOT + (size_t)(l - 1) * HLAY + (size_t)row * Hc;
      } else {
        int bb = row >> 6, aa = row & 63;
        size_t rofs = ((size_t)bb * Tc + t) * 64 + aa;
        pA[rf] = xb ? (xb + rofs * Hc) : nullptr;
        pXf[rf] = x + rofs * Hc;
      }
    }

    f32x4 acc[6][4];
#pragma unroll
    for (int m = 0; m < 6; ++m)
#pragma unroll
      for (int rf = 0; rf < 4; ++rf) acc[m][rf] = f32x4{0.f, 0.f, 0.f, 0.f};

#define KBODY(AI_LOAD)                                                              \
    _Pragma("unroll 4")                                                             \
    for (int ks = 0; ks < 16; ++ks) {                                               \
      const int kb = ks * 64 + (kgrp << 4);                                         \
      const int ke = ks * 32 + (kgrp << 3);                                         \
      bf16x8 Bg[6];                                                                 \
      _Pragma("unroll")                                                             \
      for (int m = 0; m < 6; ++m)                                                   \
        Bg[m] = *(const bf16x8*)(wlds + (m * 16 + lrow) * 1024 + (kb ^ swzB));      \
      bf16x8 Ah_[4], Ai_[4];                                                        \
      _Pragma("unroll")                                                             \
      for (int rf = 0; rf < 4; ++rf) {                                              \
        Ah_[rf] = *(const bf16x8*)(pH[rf] + ke);                                    \
        AI_LOAD(rf)                                                                 \
      }                                                                             \
      _Pragma("unroll")                                                             \
      for (int rf = 0; rf < 4; ++rf) {                                              \
        acc[0][rf] = __builtin_amdgcn_mfma_f32_16x16x32_bf16(Ai_[rf], Bg[0], acc[0][rf], 0, 0, 0); \
        acc[1][rf] = __builtin_amdgcn_mfma_f32_16x16x32_bf16(Ai_[rf], Bg[1], acc[1][rf], 0, 0, 0); \
        acc[2][rf] = __builtin_amdgcn_mfma_f32_16x16x32_bf16(Ai_[rf], Bg[2], acc[2][rf], 0, 0, 0); \
        acc[3][rf] = __builtin_amdgcn_mfma_f32_16x16x32_bf16(Ah_[rf], Bg[3], acc[3][rf], 0, 0, 0); \
        acc[4][rf] = __builtin_amdgcn_mfma_f32_16x16x32_bf16(Ah_[rf], Bg[4], acc[4][rf], 0, 0, 0); \
        acc[5][rf] = __builtin_amdgcn_mfma_f32_16x16x32_bf16(Ah_[rf], Bg[5], acc[5][rf], 0, 0, 0); \
      }                                                                             \
    }

#define AI_PTR(rf) Ai_[rf] = *(const bf16x8*)(pA[rf] + ke);
#define AI_F32(rf)                                                                  \
      {                                                                             \
        f32x4 v0 = *(const f32x4*)(pXf[rf] + ke);                                   \
        f32x4 v1 = *(const f32x4*)(pXf[rf] + ke + 4);                               \
        bf16x8 tmp;                                                                 \
        _Pragma("unroll")                                                           \
        for (int e = 0; e < 4; ++e) {                                               \
          tmp[e] = (short)f2bf(v0[e]);                                              \
          tmp[4 + e] = (short)f2bf(v1[e]);                                          \
        }                                                                           \
        Ai_[rf] = tmp;                                                              \
      }

    if (l > 0 || xb) {
      KBODY(AI_PTR)
    } else {
      KBODY(AI_F32)
    }
#undef KBODY
#undef AI_PTR
#undef AI_F32

    // epilogue: C/D map col=lane&15, row=(lane>>4)*4+reg (m89-verified)
    short* hout = hb + (size_t)par * HSLOT + (size_t)l * HLAY;
#pragma unroll
    for (int rf = 0; rf < 4; ++rf) {
#pragma unroll
      for (int rr = 0; rr < 4; ++rr) {
        int rowg = R0 + w * 64 + rf * 16 + kgrp * 4 + rr;
        int bb = rowg >> 6, aa = rowg & 63;
        size_t vofs = ((size_t)bb * Tc + t) * 64 + aa;
        int vld = valid[vofs];
        float ir = acc[0][rf][rr] + bi0;
        float iz = acc[1][rf][rr] + bi1;
        float in_ = acc[2][rf][rr] + bi2;
        float hr = acc[3][rf][rr] + bh0;
        float hz = acc[4][rf][rr] + bh1;
        float hn = acc[5][rf][rr] + bh2;
        float rg = 1.0f / (1.0f + __expf(-(ir + hr)));
        float zg = 1.0f / (1.0f + __expf(-(iz + hz)));
        float ng = tanhf(in_ + rg * hn);
        float hnew = (1.0f - zg) * ng + zg * hreg[rf][rr];
        if (!vld) hnew = 0.0f;
        hreg[rf][rr] = hnew;
        hout[(size_t)rowg * Hc + c] = (short)f2bf(hnew);
        if (l == 2) y[vofs * Hc + c] = hnew;
      }
    }

    __syncthreads();                 // all waves' reads consumed + stores drained
    if (tid == 0) {
      if (l > 0)
        __hip_atomic_fetch_add(&rd[((l - 1) * Tc + t) * 2 + rb], 1,
                               __ATOMIC_RELAXED, __HIP_MEMORY_SCOPE_AGENT);
      if (t > 0)
        __hip_atomic_fetch_add(&rd[(l * Tc + (t - 1)) * 2 + rb], 1,
                               __ATOMIC_RELAXED, __HIP_MEMORY_SCOPE_AGENT);
      __hip_atomic_fetch_add(&cnt[(l * Tc + t) * 2 + rb], 1,
                             __ATOMIC_RELEASE, __HIP_MEMORY_SCOPE_AGENT);
    }
  }
}

extern "C" void kernel_launch(void* const* d_in, const int* in_sizes, int n_in,
                              void* d_out, int out_size, void* d_ws, size_t ws_size,
                              hipStream_t stream) {
  const float* x = (const float*)d_in[0];
  const int* valid = (const int*)d_in[1];
  const float* w_ih = (const float*)d_in[2];
  const float* w_hh = (const float*)d_in[3];
  const float* b_ih = (const float*)d_in[4];
  const float* b_hh = (const float*)d_in[5];
  float* y = (float*)d_out;

  char* ws = (char*)d_ws;
  const size_t welems = (size_t)Lc * H3c * Hc;            // 2,359,296
  unsigned short* wbih = (unsigned short*)ws;             // 4.5 MB
  unsigned short* wbhh = (unsigned short*)(ws + welems * 2);
  short* hb = (short*)(ws + welems * 4);                  // 3.0 MB
  const size_t hb_bytes = (size_t)2 * HSLOT * 2;          // 3,145,728
  int* cnt = (int*)(ws + welems * 4 + hb_bytes);          // [3][100][2]
  int* rd = cnt + Lc * Tc * 2;                            // [3][100][2]
  const size_t flags_bytes = (size_t)2 * Lc * Tc * 2 * sizeof(int);
  const size_t xb_off = welems * 4 + hb_bytes + 4800;     // 12,587,712 (16B aligned)
  const size_t xelems = (size_t)8 * Tc * 64 * Hc;         // 26,214,400
  const bool big = ws_size >= xb_off + xelems * 2;
  unsigned short* xbf = big ? (unsigned short*)(ws + xb_off) : nullptr;

  int n4w = (int)(welems / 4);
  conv_bf16<<<(n4w + 255) / 256, 256, 0, stream>>>(w_ih, wbih, n4w);
  conv_bf16<<<(n4w + 255) / 256, 256, 0, stream>>>(w_hh, wbhh, n4w);
  if (big) {
    int n4x = (int)(xelems / 4);
    conv_bf16<<<(n4x + 255) / 256, 256, 0, stream>>>(x, xbf, n4x);
  }
  (void)hipMemsetAsync(hb, 0, hb_bytes + flags_bytes, stream);   // ring + flags

  gru_persist2<<<192, 256, 0, stream>>>(x, (const short*)xbf,
                                        (const short*)wbih, (const short*)wbhh,
                                        b_ih, b_hh, hb, valid, y, cnt, rd);
}

// Round 4
// 3398.917 us; speedup vs baseline: 1.4220x; 1.1608x over previous
//
#include <hip/hip_runtime.h>

#define Tc 100
#define Hc 512
#define Lc 3
#define H3c 1536
#define HLAY (Hc*Hc)            // 262144 elems per layer slice of an hb slot
#define HSLOT (Lc*HLAY)         // elems per hb parity slot

typedef short bf16x8 __attribute__((ext_vector_type(8)));
typedef float f32x4 __attribute__((ext_vector_type(4)));

__device__ __forceinline__ unsigned short f2bf(float f) {
  unsigned int u = __float_as_uint(f);
  u += 0x7FFFu + ((u >> 16) & 1u);   // round-to-nearest-even
  return (unsigned short)(u >> 16);
}

__global__ __launch_bounds__(256) void conv_bf16(const float* __restrict__ src,
                                                 unsigned short* __restrict__ dst,
                                                 int n4) {
  int i = blockIdx.x * 256 + threadIdx.x;
  if (i >= n4) return;
  f32x4 v = *(const f32x4*)(src + (size_t)i * 4);
  ushort4 o;
  o.x = f2bf(v[0]); o.y = f2bf(v[1]); o.z = f2bf(v[2]); o.w = f2bf(v[3]);
  *(ushort4*)(dst + (size_t)i * 4) = o;
}

// Relaxed poll only — NO acquire fence (no buffer_inv). Data is read with
// per-access coherent (sc0 sc1) loads, so no cache invalidation is needed.
__device__ __forceinline__ void spin_rlx(int* p, int tgt) {
  int it = 0;
  while (__hip_atomic_load(p, __ATOMIC_RELAXED, __HIP_MEMORY_SCOPE_AGENT) < tgt) {
    __builtin_amdgcn_s_sleep(1);
    if (++it > 8000000) break;      // deadlock bug -> fast fail, not hang
  }
}

// Coherent (read/write the coherence point, bypass stale L1/L2) vs normal loads.
#define LOADC(dst, ptr) \
  asm volatile("global_load_dwordx4 %0, %1, off sc0 sc1" : "=v"(dst) : "v"(ptr))
#define LOADN(dst, ptr) \
  asm volatile("global_load_dwordx4 %0, %1, off" : "=v"(dst) : "v"(ptr))
#define STORE_H2(ptr, v32) \
  asm volatile("global_store_short %0, %1, off sc0 sc1" :: "v"(ptr), "v"(v32))
#define WAITV(n) do { asm volatile("s_waitcnt vmcnt(" #n ")" ::: "memory"); \
                      __builtin_amdgcn_sched_barrier(0); } while (0)
#define MM(a, b, c) c = __builtin_amdgcn_mfma_f32_16x16x32_bf16(a, b, c, 0, 0, 0)

// Persistent dataflow GRU, weights LDS-resident, coherent h-ring, no fences.
// 192 blocks x 256 thr (1 block/CU). Block = (l, rb: 256 rows, cb: 16 cols).
// LDS: 96 B-fragments (6 mats x 16 k-slots) x 64 lanes x 16 B, linear per-lane
// (each lane writes exactly the bytes it later reads -> conflict-free).
// K-loop: double-buffered asm loads (16 in flight) with counted vmcnt.
__global__ __launch_bounds__(256, 1) void gru_persist3(
    const float* __restrict__ x,     // [B,T,A,H] f32 (fallback)
    const short* __restrict__ xb,    // [B,T,A,H] bf16 or nullptr
    const short* __restrict__ wbih,  // [L,3H,H] bf16
    const short* __restrict__ wbhh,  // [L,3H,H] bf16
    const float* __restrict__ bih,   // [L,3H]
    const float* __restrict__ bhh,   // [L,3H]
    short* hb,                       // [2][L][512][512] bf16 parity ring (sc-access only)
    const int* __restrict__ valid,   // [B,T,A] int32
    float* __restrict__ y,           // [B,T,A,H] f32
    int* cnt, int* rd) {
  __shared__ char wlds[98304];

  const int bid = blockIdx.x;
  const int xcd = bid & 7;
  const int q = bid >> 3;            // 0..23
  const int l = q % 3;
  const int u = q / 3;               // 0..7
  const int rb = u & 1;
  const int cb = (u >> 1) * 8 + xcd; // 0..31
  const int c0 = cb * 16;
  const int R0 = rb * 256;

  const int tid = threadIdx.x;
  const int w = tid >> 6;
  const int lane = tid & 63;
  const int lrow = lane & 15;
  const int kgrp = lane >> 4;

  const short* wih_l = wbih + (size_t)l * H3c * Hc;
  const short* whh_l = wbhh + (size_t)l * H3c * Hc;

  // ---- one-time LDS weight fill: frag j = m*16+ks, lane-linear, no swizzle.
  // frag(m,ks,lane) = Wmat[n = g*512 + c0 + lrow][ks*32 + kgrp*8 .. +8)
#pragma unroll
  for (int j4 = 0; j4 < 24; ++j4) {
    int j = j4 * 4 + w;
    int m = j >> 4, ks = j & 15;
    int g = (m < 3) ? m : m - 3;
    int n = g * Hc + c0 + lrow;
    const short* src = ((m < 3) ? wih_l : whh_l) + (size_t)n * Hc + ks * 32 + kgrp * 8;
    *(bf16x8*)(wlds + (size_t)j * 1024 + lane * 16) = *(const bf16x8*)src;
  }
  __syncthreads();

  const char* wl = wlds + (lane << 4);

  const float* bihl = bih + l * H3c;
  const float* bhhl = bhh + l * H3c;
  const int c = c0 + lrow;
  const float bi0 = bihl[c], bi1 = bihl[Hc + c], bi2 = bihl[2 * Hc + c];
  const float bh0 = bhhl[c], bh1 = bhhl[Hc + c], bh2 = bhhl[2 * Hc + c];

  f32x4 hreg[4];
#pragma unroll
  for (int rf = 0; rf < 4; ++rf) hreg[rf] = f32x4{0.f, 0.f, 0.f, 0.f};

  for (int t = 0; t < Tc; ++t) {
    // parallel flag waits on 3 different waves (relaxed, no fence)
    if (tid == 0 && l > 0) spin_rlx(&cnt[((l - 1) * Tc + t) * 2 + rb], 32);
    if (tid == 64 && t > 0) spin_rlx(&cnt[(l * Tc + (t - 1)) * 2 + rb], 32);
    if (tid == 128 && t >= 2) spin_rlx(&rd[(l * Tc + (t - 2)) * 2 + rb], 32 + (l < 2 ? 32 : 0));
    __syncthreads();

    const int par = t & 1;
    const short* hprev = hb + (size_t)(1 - par) * HSLOT + (size_t)l * HLAY;

    const short* pH[4];
    const short* pA[4] = {nullptr, nullptr, nullptr, nullptr};
    const float* pXf[4] = {x, x, x, x};
#pragma unroll
    for (int rf = 0; rf < 4; ++rf) {
      int row = R0 + w * 64 + rf * 16 + lrow;
      pH[rf] = hprev + (size_t)row * Hc;
      if (l > 0) {
        pA[rf] = hb + (size_t)par * HSLOT + (size_t)(l - 1) * HLAY + (size_t)row * Hc;
      } else {
        int bb = row >> 6, aa = row & 63;
        size_t rofs = ((size_t)bb * Tc + t) * 64 + aa;
        if (xb) pA[rf] = xb + rofs * Hc;
        pXf[rf] = x + rofs * Hc;
      }
    }

    f32x4 acc[6][4];
#pragma unroll
    for (int m = 0; m < 6; ++m)
#pragma unroll
      for (int rf = 0; rf < 4; ++rf) acc[m][rf] = f32x4{0.f, 0.f, 0.f, 0.f};

#define AI_ISSUE_C(I_, rf, k2, addr) LOADC(I_[rf][k2], addr)
#define AI_ISSUE_N(I_, rf, k2, addr) LOADN(I_[rf][k2], addr)
#define AI_ISSUE_X(I_, rf, k2, addr)
#define AI_GET_REG(dst, I_, rf, k2, ks) dst = I_[rf][k2]
#define AI_GET_F32(dst, I_, rf, k2, ks)                                            \
      {                                                                            \
        const float* _px = pXf[rf] + (ks) * 32 + (kgrp << 3);                      \
        f32x4 v0 = *(const f32x4*)_px;                                             \
        f32x4 v1 = *(const f32x4*)(_px + 4);                                       \
        bf16x8 t_;                                                                 \
        _Pragma("unroll") for (int e = 0; e < 4; ++e) {                            \
          t_[e] = (short)f2bf(v0[e]); t_[4 + e] = (short)f2bf(v1[e]);              \
        }                                                                          \
        dst = t_;                                                                  \
      }

#define ISSUE(H_, I_, g2, AI_ISS)                                                  \
      { _Pragma("unroll") for (int rf = 0; rf < 4; ++rf)                           \
          _Pragma("unroll") for (int k2 = 0; k2 < 2; ++k2) {                       \
            const int ke = ((g2) * 2 + k2) * 32 + (kgrp << 3);                     \
            LOADC(H_[rf][k2], pH[rf] + ke);                                        \
            AI_ISS(I_, rf, k2, pA[rf] + ke);                                       \
          } }

#define CONSUME(H_, I_, g2, AI_GET)                                                \
      { _Pragma("unroll") for (int k2 = 0; k2 < 2; ++k2) {                         \
          const int ks = (g2) * 2 + k2;                                            \
          bf16x8 Bg0 = *(const bf16x8*)(wl + ((0 * 16 + ks) << 10));               \
          bf16x8 Bg1 = *(const bf16x8*)(wl + ((1 * 16 + ks) << 10));               \
          bf16x8 Bg2 = *(const bf16x8*)(wl + ((2 * 16 + ks) << 10));               \
          bf16x8 Bg3 = *(const bf16x8*)(wl + ((3 * 16 + ks) << 10));               \
          bf16x8 Bg4 = *(const bf16x8*)(wl + ((4 * 16 + ks) << 10));               \
          bf16x8 Bg5 = *(const bf16x8*)(wl + ((5 * 16 + ks) << 10));               \
          _Pragma("unroll") for (int rf = 0; rf < 4; ++rf) {                       \
            bf16x8 Ai_; AI_GET(Ai_, I_, rf, k2, ks);                               \
            MM(Ai_, Bg0, acc[0][rf]);                                              \
            MM(Ai_, Bg1, acc[1][rf]);                                              \
            MM(Ai_, Bg2, acc[2][rf]);                                              \
            MM(H_[rf][k2], Bg3, acc[3][rf]);                                       \
            MM(H_[rf][k2], Bg4, acc[4][rf]);                                       \
            MM(H_[rf][k2], Bg5, acc[5][rf]);                                       \
          } } }

#define KLOOP(AI_ISS, AI_GET, WMID)                                                \
      {                                                                            \
        bf16x8 gHa[4][2], gIa[4][2], gHb[4][2], gIb[4][2];                         \
        ISSUE(gHa, gIa, 0, AI_ISS);                                                \
        _Pragma("unroll") for (int g2 = 0; g2 < 8; g2 += 2) {                      \
          ISSUE(gHb, gIb, g2 + 1, AI_ISS);                                         \
          WAITV(WMID);                                                             \
          CONSUME(gHa, gIa, g2, AI_GET);                                           \
          if (g2 + 2 < 8) {                                                        \
            ISSUE(gHa, gIa, g2 + 2, AI_ISS);                                       \
            WAITV(WMID);                                                           \
          } else {                                                                 \
            WAITV(0);                                                              \
          }                                                                        \
          CONSUME(gHb, gIb, g2 + 1, AI_GET);                                       \
        }                                                                          \
      }

    if (l > 0) {
      KLOOP(AI_ISSUE_C, AI_GET_REG, 16)
    } else if (xb) {
      KLOOP(AI_ISSUE_N, AI_GET_REG, 16)
    } else {
      KLOOP(AI_ISSUE_X, AI_GET_F32, 8)
    }

    // epilogue: C/D map col=lane&15, row=(lane>>4)*4+reg (m89-verified)
    short* hout = hb + (size_t)par * HSLOT + (size_t)l * HLAY;
#pragma unroll
    for (int rf = 0; rf < 4; ++rf) {
#pragma unroll
      for (int rr = 0; rr < 4; ++rr) {
        int rowg = R0 + w * 64 + rf * 16 + kgrp * 4 + rr;
        int bb = rowg >> 6, aa = rowg & 63;
        size_t vofs = ((size_t)bb * Tc + t) * 64 + aa;
        int vld = valid[vofs];
        float ir = acc[0][rf][rr] + bi0;
        float iz = acc[1][rf][rr] + bi1;
        float in_ = acc[2][rf][rr] + bi2;
        float hr = acc[3][rf][rr] + bh0;
        float hz = acc[4][rf][rr] + bh1;
        float hn = acc[5][rf][rr] + bh2;
        float rg = 1.0f / (1.0f + __expf(-(ir + hr)));
        float zg = 1.0f / (1.0f + __expf(-(iz + hz)));
        float ng = tanhf(in_ + rg * hn);
        float hnew = (1.0f - zg) * ng + zg * hreg[rf][rr];
        if (!vld) hnew = 0.0f;
        hreg[rf][rr] = hnew;
        int hv = (int)f2bf(hnew);
        STORE_H2(hout + (size_t)rowg * Hc + c, hv);
        if (l == 2) y[vofs * Hc + c] = hnew;
      }
    }

    asm volatile("s_waitcnt vmcnt(0)" ::: "memory");   // sc stores at coherence point
    __syncthreads();
    if (tid == 0) {
      if (l > 0)
        __hip_atomic_fetch_add(&rd[((l - 1) * Tc + t) * 2 + rb], 1,
                               __ATOMIC_RELAXED, __HIP_MEMORY_SCOPE_AGENT);
      if (t > 0)
        __hip_atomic_fetch_add(&rd[(l * Tc + (t - 1)) * 2 + rb], 1,
                               __ATOMIC_RELAXED, __HIP_MEMORY_SCOPE_AGENT);
      __hip_atomic_fetch_add(&cnt[(l * Tc + t) * 2 + rb], 1,
                             __ATOMIC_RELEASE, __HIP_MEMORY_SCOPE_AGENT);
    }
  }
}

extern "C" void kernel_launch(void* const* d_in, const int* in_sizes, int n_in,
                              void* d_out, int out_size, void* d_ws, size_t ws_size,
                              hipStream_t stream) {
  const float* x = (const float*)d_in[0];
  const int* valid = (const int*)d_in[1];
  const float* w_ih = (const float*)d_in[2];
  const float* w_hh = (const float*)d_in[3];
  const float* b_ih = (const float*)d_in[4];
  const float* b_hh = (const float*)d_in[5];
  float* y = (float*)d_out;

  char* ws = (char*)d_ws;
  const size_t welems = (size_t)Lc * H3c * Hc;            // 2,359,296
  unsigned short* wbih = (unsigned short*)ws;             // 4.5 MB
  unsigned short* wbhh = (unsigned short*)(ws + welems * 2);
  short* hb = (short*)(ws + welems * 4);                  // 3.0 MB
  const size_t hb_bytes = (size_t)2 * HSLOT * 2;          // 3,145,728
  int* cnt = (int*)(ws + welems * 4 + hb_bytes);          // [3][100][2]
  int* rd = cnt + Lc * Tc * 2;                            // [3][100][2]
  const size_t flags_bytes = (size_t)2 * Lc * Tc * 2 * sizeof(int);
  const size_t xb_off = welems * 4 + hb_bytes + 4800;     // 16B aligned
  const size_t xelems = (size_t)8 * Tc * 64 * Hc;         // 26,214,400
  const bool big = ws_size >= xb_off + xelems * 2;
  unsigned short* xbf = big ? (unsigned short*)(ws + xb_off) : nullptr;

  int n4w = (int)(welems / 4);
  conv_bf16<<<(n4w + 255) / 256, 256, 0, stream>>>(w_ih, wbih, n4w);
  conv_bf16<<<(n4w + 255) / 256, 256, 0, stream>>>(w_hh, wbhh, n4w);
  if (big) {
    int n4x = (int)(xelems / 4);
    conv_bf16<<<(n4x + 255) / 256, 256, 0, stream>>>(x, xbf, n4x);
  }
  (void)hipMemsetAsync(hb, 0, hb_bytes + flags_bytes, stream);   // ring + flags

  gru_persist3<<<192, 256, 0, stream>>>(x, (const short*)xbf,
                                        (const short*)wbih, (const short*)wbhh,
                                        b_ih, b_hh, hb, valid, y, cnt, rd);
}

// Round 7
// 2975.254 us; speedup vs baseline: 1.6245x; 1.1424x over previous
//
#include <hip/hip_runtime.h>

#define Tc 100
#define Hc 512
#define Lc 3
#define H3c 1536
#define HLAY (Hc*Hc)            // elems per layer slice of an hb parity slot
#define HSLOT (Lc*HLAY)         // elems per parity slot

typedef short bf16x8 __attribute__((ext_vector_type(8)));
typedef float f32x4 __attribute__((ext_vector_type(4)));

__device__ __forceinline__ unsigned short f2bf(float f) {
  unsigned int u = __float_as_uint(f);
  u += 0x7FFFu + ((u >> 16) & 1u);   // round-to-nearest-even
  return (unsigned short)(u >> 16);
}

__global__ __launch_bounds__(256) void conv_bf16(const float* __restrict__ src,
                                                 unsigned short* __restrict__ dst,
                                                 int n4) {
  int i = blockIdx.x * 256 + threadIdx.x;
  if (i >= n4) return;
  f32x4 v = *(const f32x4*)(src + (size_t)i * 4);
  ushort4 o;
  o.x = f2bf(v[0]); o.y = f2bf(v[1]); o.z = f2bf(v[2]); o.w = f2bf(v[3]);
  *(ushort4*)(dst + (size_t)i * 4) = o;
}

// Poll the coherence point directly: sc0sc1 dword load + self-drain vmcnt(0).
// No acquire fence (no buffer_inv), no reliance on atomic-load lowering,
// no vmcnt leakage (drained inside).
__device__ __forceinline__ void spinC(const int* p, int tgt) {
  int it = 0;
  for (;;) {
    int v;
    asm volatile("global_load_dword %0, %1, off sc0 sc1\n\ts_waitcnt vmcnt(0)"
                 : "=v"(v) : "v"(p) : "memory");
    if (v >= tgt) break;
    __builtin_amdgcn_s_sleep(1);
    if (++it > 8000000) break;      // deadlock bug -> fast fail, not hang
  }
}

#define LOADC(dst, ptr) \
  asm volatile("global_load_dwordx4 %0, %1, off sc0 sc1" : "=v"(dst) : "v"(ptr))
#define LOADN(dst, ptr) \
  asm volatile("global_load_dwordx4 %0, %1, off" : "=v"(dst) : "v"(ptr))
#define STORE_H2(ptr, v32) \
  asm volatile("global_store_short %0, %1, off sc0 sc1" :: "v"(ptr), "v"(v32))
#define WAITV(n) do { asm volatile("s_waitcnt vmcnt(" #n ")" ::: "memory"); \
                      __builtin_amdgcn_sched_barrier(0); } while (0)
#define MM(a, b, c) c = __builtin_amdgcn_mfma_f32_16x16x32_bf16(a, b, c, 0, 0, 0)

// Persistent dataflow GRU — persist3 skeleton (proven correct) with
// (a) RELAXED cnt publish (no buffer_wbl2 per stage),
// (b) coherence-point polls (spinC), (c) vmcnt hygiene fences.
// 192 blocks x 256 thr (1 block/CU). Block = (l, rb: 256 rows, cb: 16 cols).
// LDS: 96 B-fragments (6 mats x 16 k-slots) x 64 lanes x 16 B, lane-linear.
// h ring: [2][L][512][512] bf16 row-major, sc0sc1 access only.
__global__ __launch_bounds__(256, 1) void gru_persist6(
    const float* __restrict__ x,     // [B,T,A,H] f32 (fallback)
    const short* __restrict__ xb,    // [B,T,A,H] bf16 or nullptr
    const short* __restrict__ wbih,  // [L,3H,H] bf16
    const short* __restrict__ wbhh,  // [L,3H,H] bf16
    const float* __restrict__ bih,   // [L,3H]
    const float* __restrict__ bhh,   // [L,3H]
    short* hb,                       // [2][L][512][512] bf16 parity ring
    const int* __restrict__ valid,   // [B,T,A] int32
    float* __restrict__ y,           // [B,T,A,H] f32
    int* cnt, int* rd) {
  __shared__ char wlds[98304];

  const int bid = blockIdx.x;
  const int xcd = bid & 7;
  const int q = bid >> 3;            // 0..23
  const int l = q % 3;
  const int u = q / 3;               // 0..7
  const int rb = u & 1;
  const int cb = (u >> 1) * 8 + xcd; // 0..31
  const int c0 = cb * 16;
  const int R0 = rb * 256;

  const int tid = threadIdx.x;
  const int w = tid >> 6;
  const int lane = tid & 63;
  const int lrow = lane & 15;
  const int kgrp = lane >> 4;

  const short* wih_l = wbih + (size_t)l * H3c * Hc;
  const short* whh_l = wbhh + (size_t)l * H3c * Hc;

  // ---- one-time LDS weight fill: frag j = m*16+ks, lane-linear ----
#pragma unroll
  for (int j4 = 0; j4 < 24; ++j4) {
    int j = j4 * 4 + w;
    int m = j >> 4, ks = j & 15;
    int g = (m < 3) ? m : m - 3;
    int n = g * Hc + c0 + lrow;
    const short* src = ((m < 3) ? wih_l : whh_l) + (size_t)n * Hc + ks * 32 + kgrp * 8;
    *(bf16x8*)(wlds + (size_t)j * 1024 + lane * 16) = *(const bf16x8*)src;
  }
  __syncthreads();

  const char* wl = wlds + (lane << 4);

  const float* bihl = bih + l * H3c;
  const float* bhhl = bhh + l * H3c;
  const int c = c0 + lrow;
  const float bi0 = bihl[c], bi1 = bihl[Hc + c], bi2 = bihl[2 * Hc + c];
  const float bh0 = bhhl[c], bh1 = bhhl[Hc + c], bh2 = bhhl[2 * Hc + c];

  f32x4 hreg[4];
#pragma unroll
  for (int rf = 0; rf < 4; ++rf) hreg[rf] = f32x4{0.f, 0.f, 0.f, 0.f};

  WAITV(0);                          // setup loads drained before counted regions

  for (int t = 0; t < Tc; ++t) {
    // parallel flag waits on 3 different waves (coherence-point polls)
    if (tid == 0 && l > 0) spinC(&cnt[((l - 1) * Tc + t) * 2 + rb], 32);
    if (tid == 64 && t > 0) spinC(&cnt[(l * Tc + (t - 1)) * 2 + rb], 32);
    if (tid == 128 && t >= 2) spinC(&rd[(l * Tc + (t - 2)) * 2 + rb], 32 + (l < 2 ? 32 : 0));
    __syncthreads();

    const int par = t & 1;
    const short* hprev = hb + (size_t)(1 - par) * HSLOT + (size_t)l * HLAY;

    const short* pH[4];
    const short* pA[4] = {nullptr, nullptr, nullptr, nullptr};
    const float* pXf[4] = {x, x, x, x};
#pragma unroll
    for (int rf = 0; rf < 4; ++rf) {
      int row = R0 + w * 64 + rf * 16 + lrow;
      pH[rf] = hprev + (size_t)row * Hc;
      if (l > 0) {
        pA[rf] = hb + (size_t)par * HSLOT + (size_t)(l - 1) * HLAY + (size_t)row * Hc;
      } else {
        int bb = row >> 6, aa = row & 63;
        size_t rofs = ((size_t)bb * Tc + t) * 64 + aa;
        if (xb) pA[rf] = xb + rofs * Hc;
        pXf[rf] = x + rofs * Hc;
      }
    }

    f32x4 acc[6][4];
#pragma unroll
    for (int m = 0; m < 6; ++m)
#pragma unroll
      for (int rf = 0; rf < 4; ++rf) acc[m][rf] = f32x4{0.f, 0.f, 0.f, 0.f};

#define AI_ISSUE_C(I_, rf, k2, addr) LOADC(I_[rf][k2], addr)
#define AI_ISSUE_N(I_, rf, k2, addr) LOADN(I_[rf][k2], addr)
#define AI_ISSUE_X(I_, rf, k2, addr)
#define AI_GET_REG(dst, I_, rf, k2, ks) dst = I_[rf][k2]
#define AI_GET_F32(dst, I_, rf, k2, ks)                                            \
      {                                                                            \
        const float* _px = pXf[rf] + (ks) * 32 + (kgrp << 3);                      \
        f32x4 v0 = *(const f32x4*)_px;                                             \
        f32x4 v1 = *(const f32x4*)(_px + 4);                                       \
        bf16x8 t_;                                                                 \
        _Pragma("unroll") for (int e = 0; e < 4; ++e) {                            \
          t_[e] = (short)f2bf(v0[e]); t_[4 + e] = (short)f2bf(v1[e]);              \
        }                                                                          \
        dst = t_;                                                                  \
      }

#define ISSUE(H_, I_, g2, AI_ISS)                                                  \
      { _Pragma("unroll") for (int rf = 0; rf < 4; ++rf)                           \
          _Pragma("unroll") for (int k2 = 0; k2 < 2; ++k2) {                       \
            const int ke = ((g2) * 2 + k2) * 32 + (kgrp << 3);                     \
            LOADC(H_[rf][k2], pH[rf] + ke);                                        \
            AI_ISS(I_, rf, k2, pA[rf] + ke);                                       \
          } }

#define CONSUME(H_, I_, g2, AI_GET)                                                \
      { _Pragma("unroll") for (int k2 = 0; k2 < 2; ++k2) {                         \
          const int ks = (g2) * 2 + k2;                                            \
          bf16x8 Bg0 = *(const bf16x8*)(wl + ((0 * 16 + ks) << 10));               \
          bf16x8 Bg1 = *(const bf16x8*)(wl + ((1 * 16 + ks) << 10));               \
          bf16x8 Bg2 = *(const bf16x8*)(wl + ((2 * 16 + ks) << 10));               \
          bf16x8 Bg3 = *(const bf16x8*)(wl + ((3 * 16 + ks) << 10));               \
          bf16x8 Bg4 = *(const bf16x8*)(wl + ((4 * 16 + ks) << 10));               \
          bf16x8 Bg5 = *(const bf16x8*)(wl + ((5 * 16 + ks) << 10));               \
          _Pragma("unroll") for (int rf = 0; rf < 4; ++rf) {                       \
            bf16x8 Ai_; AI_GET(Ai_, I_, rf, k2, ks);                               \
            MM(Ai_, Bg0, acc[0][rf]);                                              \
            MM(Ai_, Bg1, acc[1][rf]);                                              \
            MM(Ai_, Bg2, acc[2][rf]);                                              \
            MM(H_[rf][k2], Bg3, acc[3][rf]);                                       \
            MM(H_[rf][k2], Bg4, acc[4][rf]);                                       \
            MM(H_[rf][k2], Bg5, acc[5][rf]);                                       \
          } } }

#define KLOOP(AI_ISS, AI_GET, WMID)                                                \
      {                                                                            \
        bf16x8 gHa[4][2], gIa[4][2], gHb[4][2], gIb[4][2];                         \
        ISSUE(gHa, gIa, 0, AI_ISS);                                                \
        _Pragma("unroll") for (int g2 = 0; g2 < 8; g2 += 2) {                      \
          ISSUE(gHb, gIb, g2 + 1, AI_ISS);                                         \
          WAITV(WMID);                                                             \
          CONSUME(gHa, gIa, g2, AI_GET);                                           \
          if (g2 + 2 < 8) {                                                        \
            ISSUE(gHa, gIa, g2 + 2, AI_ISS);                                       \
            WAITV(WMID);                                                           \
          } else {                                                                 \
            WAITV(0);                                                              \
          }                                                                        \
          CONSUME(gHb, gIb, g2 + 1, AI_GET);                                       \
        }                                                                          \
      }

    __builtin_amdgcn_sched_barrier(0);
    if (l > 0) {
      KLOOP(AI_ISSUE_C, AI_GET_REG, 16)
    } else if (xb) {
      KLOOP(AI_ISSUE_N, AI_GET_REG, 16)
    } else {
      KLOOP(AI_ISSUE_X, AI_GET_F32, 8)
    }
    __builtin_amdgcn_sched_barrier(0);

    // epilogue: C/D map col=lane&15, row=(lane>>4)*4+reg (m89-verified)
    short* hout = hb + (size_t)par * HSLOT + (size_t)l * HLAY;
#pragma unroll
    for (int rf = 0; rf < 4; ++rf) {
#pragma unroll
      for (int rr = 0; rr < 4; ++rr) {
        int rowg = R0 + w * 64 + rf * 16 + kgrp * 4 + rr;
        int bb = rowg >> 6, aa = rowg & 63;
        size_t vofs = ((size_t)bb * Tc + t) * 64 + aa;
        int vld = valid[vofs];
        float ir = acc[0][rf][rr] + bi0;
        float iz = acc[1][rf][rr] + bi1;
        float in_ = acc[2][rf][rr] + bi2;
        float hr = acc[3][rf][rr] + bh0;
        float hz = acc[4][rf][rr] + bh1;
        float hn = acc[5][rf][rr] + bh2;
        float rg = 1.0f / (1.0f + __expf(-(ir + hr)));
        float zg = 1.0f / (1.0f + __expf(-(iz + hz)));
        float ng = tanhf(in_ + rg * hn);
        float hnew = (1.0f - zg) * ng + zg * hreg[rf][rr];
        if (!vld) hnew = 0.0f;
        hreg[rf][rr] = hnew;
        int hv = (int)f2bf(hnew);
        STORE_H2(hout + (size_t)rowg * Hc + c, hv);
        if (l == 2) y[vofs * Hc + c] = hnew;
      }
    }

    asm volatile("s_waitcnt vmcnt(0)" ::: "memory");   // sc stores + y at coherence point
    __syncthreads();
    if (tid == 0) {                  // all RELAXED: no wbl2, no inv
      if (l > 0)
        __hip_atomic_fetch_add(&rd[((l - 1) * Tc + t) * 2 + rb], 1,
                               __ATOMIC_RELAXED, __HIP_MEMORY_SCOPE_AGENT);
      if (t > 0)
        __hip_atomic_fetch_add(&rd[(l * Tc + (t - 1)) * 2 + rb], 1,
                               __ATOMIC_RELAXED, __HIP_MEMORY_SCOPE_AGENT);
      __hip_atomic_fetch_add(&cnt[(l * Tc + t) * 2 + rb], 1,
                             __ATOMIC_RELAXED, __HIP_MEMORY_SCOPE_AGENT);
    }
    WAITV(0);   // drain wave-0's flag RMWs: vmcnt clean for next counted region
  }
}

extern "C" void kernel_launch(void* const* d_in, const int* in_sizes, int n_in,
                              void* d_out, int out_size, void* d_ws, size_t ws_size,
                              hipStream_t stream) {
  const float* x = (const float*)d_in[0];
  const int* valid = (const int*)d_in[1];
  const float* w_ih = (const float*)d_in[2];
  const float* w_hh = (const float*)d_in[3];
  const float* b_ih = (const float*)d_in[4];
  const float* b_hh = (const float*)d_in[5];
  float* y = (float*)d_out;

  char* ws = (char*)d_ws;
  const size_t welems = (size_t)Lc * H3c * Hc;            // 2,359,296
  unsigned short* wbih = (unsigned short*)ws;
  unsigned short* wbhh = (unsigned short*)(ws + welems * 2);
  short* hb = (short*)(ws + welems * 4);                  // 3.0 MB ring
  const size_t hb_bytes = (size_t)2 * HSLOT * 2;
  int* cnt = (int*)(ws + welems * 4 + hb_bytes);          // [3][100][2]
  int* rd = cnt + Lc * Tc * 2;                            // [3][100][2]
  const size_t flags_bytes = (size_t)2 * Lc * Tc * 2 * sizeof(int);
  const size_t xb_off = welems * 4 + hb_bytes + 4800;     // 16B aligned
  const size_t xelems = (size_t)8 * Tc * 64 * Hc;         // 26,214,400
  const bool big = ws_size >= xb_off + xelems * 2;
  unsigned short* xbf = big ? (unsigned short*)(ws + xb_off) : nullptr;

  int n4w = (int)(welems / 4);
  conv_bf16<<<(n4w + 255) / 256, 256, 0, stream>>>(w_ih, wbih, n4w);
  conv_bf16<<<(n4w + 255) / 256, 256, 0, stream>>>(w_hh, wbhh, n4w);
  if (big) {
    int n4x = (int)(xelems / 4);
    conv_bf16<<<(n4x + 255) / 256, 256, 0, stream>>>(x, xbf, n4x);
  }
  (void)hipMemsetAsync(hb, 0, hb_bytes + flags_bytes, stream);

  gru_persist6<<<192, 256, 0, stream>>>(x, (const short*)xbf,
                                        (const short*)wbih, (const short*)wbhh,
                                        b_ih, b_hh, hb, valid, y, cnt, rd);
}

// Round 8
// 2668.427 us; speedup vs baseline: 1.8112x; 1.1150x over previous
//
#include <hip/hip_runtime.h>

#define Tc 100
#define Hc 512
#define Lc 3
#define H3c 1536
#define HLAY (Hc*Hc)            // elems per layer slice of an hb parity slot
#define HSLOT (Lc*HLAY)         // elems per parity slot

typedef short bf16x8 __attribute__((ext_vector_type(8)));
typedef float f32x4 __attribute__((ext_vector_type(4)));

__device__ __forceinline__ unsigned short f2bf(float f) {
  unsigned int u = __float_as_uint(f);
  u += 0x7FFFu + ((u >> 16) & 1u);   // round-to-nearest-even
  return (unsigned short)(u >> 16);
}

__global__ __launch_bounds__(256) void conv_bf16(const float* __restrict__ src,
                                                 unsigned short* __restrict__ dst,
                                                 int n4) {
  int i = blockIdx.x * 256 + threadIdx.x;
  if (i >= n4) return;
  f32x4 v = *(const f32x4*)(src + (size_t)i * 4);
  ushort4 o;
  o.x = f2bf(v[0]); o.y = f2bf(v[1]); o.z = f2bf(v[2]); o.w = f2bf(v[3]);
  *(ushort4*)(dst + (size_t)i * 4) = o;
}

// Lane-parallel group wait on 32 monotonic per-producer counters (store-
// published, never RMW'd). One coalesced sc0sc1 load serves the whole group;
// ballot across the wave decides. Self-draining vmcnt.
__device__ __forceinline__ void waitg(const int* slots, int tgt, int lane) {
  const int* p = slots + (lane & 31);
  int it = 0;
  for (;;) {
    int v;
    asm volatile("global_load_dword %0, %1, off sc0 sc1\n\ts_waitcnt vmcnt(0)"
                 : "=v"(v) : "v"(p) : "memory");
    if (__all(v >= tgt)) break;
    __builtin_amdgcn_s_sleep(1);
    if (++it > 4000000) break;      // deadlock bug -> fast fail, not hang
  }
}

#define LOADC(dst, ptr) \
  asm volatile("global_load_dwordx4 %0, %1, off sc0 sc1" : "=v"(dst) : "v"(ptr))
#define LOADN(dst, ptr) \
  asm volatile("global_load_dwordx4 %0, %1, off" : "=v"(dst) : "v"(ptr))
#define STORE_H2(ptr, v32) \
  asm volatile("global_store_short %0, %1, off sc0 sc1" :: "v"(ptr), "v"(v32))
#define STORE_D(ptr, v32) \
  asm volatile("global_store_dword %0, %1, off sc0 sc1" :: "v"(ptr), "v"(v32))
#define WAITV(n) do { asm volatile("s_waitcnt vmcnt(" #n ")" ::: "memory"); \
                      __builtin_amdgcn_sched_barrier(0); } while (0)
#define MM(a, b, c) c = __builtin_amdgcn_mfma_f32_16x16x32_bf16(a, b, c, 0, 0, 0)

// Persistent dataflow GRU — round-7 data path (proven: LDS weights, sc0sc1
// h-ring, counted-vmcnt K-loop) with an RMW-FREE flag protocol:
// done[gi=l*2+rb][cb] = number of completed steps by block (l,rb,cb),
// published by a single sc dword STORE (no atomic RMW chain, no false
// sharing: 128B per group). Waits (3 waves in parallel, lane-parallel polls):
//   W1 (ain RAW,  l>0):        done[l-1,rb][*] >= t+1
//   W2 (hprev RAW+WAR, t>0):   done[l,  rb][*] >= t
//   W3 (ain WAR, l<2, t>=2):   done[l+1,rb][*] >= t-1
__global__ __launch_bounds__(256, 1) void gru_persist7(
    const float* __restrict__ x,     // [B,T,A,H] f32 (fallback)
    const short* __restrict__ xb,    // [B,T,A,H] bf16 or nullptr
    const short* __restrict__ wbih,  // [L,3H,H] bf16
    const short* __restrict__ wbhh,  // [L,3H,H] bf16
    const float* __restrict__ bih,   // [L,3H]
    const float* __restrict__ bhh,   // [L,3H]
    short* hb,                       // [2][L][512][512] bf16 parity ring
    const int* __restrict__ valid,   // [B,T,A] int32
    float* __restrict__ y,           // [B,T,A,H] f32
    int* done) {                     // [6][32] monotonic counters
  __shared__ char wlds[98304];

  const int bid = blockIdx.x;
  const int xcd = bid & 7;
  const int q = bid >> 3;            // 0..23
  const int l = q % 3;
  const int u = q / 3;               // 0..7
  const int rb = u & 1;
  const int cb = (u >> 1) * 8 + xcd; // 0..31
  const int c0 = cb * 16;
  const int R0 = rb * 256;
  const int gi = l * 2 + rb;

  const int tid = threadIdx.x;
  const int w = tid >> 6;
  const int lane = tid & 63;
  const int lrow = lane & 15;
  const int kgrp = lane >> 4;

  const short* wih_l = wbih + (size_t)l * H3c * Hc;
  const short* whh_l = wbhh + (size_t)l * H3c * Hc;

  // ---- one-time LDS weight fill: frag j = m*16+ks, lane-linear ----
#pragma unroll
  for (int j4 = 0; j4 < 24; ++j4) {
    int j = j4 * 4 + w;
    int m = j >> 4, ks = j & 15;
    int g = (m < 3) ? m : m - 3;
    int n = g * Hc + c0 + lrow;
    const short* src = ((m < 3) ? wih_l : whh_l) + (size_t)n * Hc + ks * 32 + kgrp * 8;
    *(bf16x8*)(wlds + (size_t)j * 1024 + lane * 16) = *(const bf16x8*)src;
  }
  __syncthreads();

  const char* wl = wlds + (lane << 4);

  const float* bihl = bih + l * H3c;
  const float* bhhl = bhh + l * H3c;
  const int c = c0 + lrow;
  const float bi0 = bihl[c], bi1 = bihl[Hc + c], bi2 = bihl[2 * Hc + c];
  const float bh0 = bhhl[c], bh1 = bhhl[Hc + c], bh2 = bhhl[2 * Hc + c];

  f32x4 hreg[4];
#pragma unroll
  for (int rf = 0; rf < 4; ++rf) hreg[rf] = f32x4{0.f, 0.f, 0.f, 0.f};

  WAITV(0);                          // setup loads drained before counted regions

  for (int t = 0; t < Tc; ++t) {
    // parallel waits on 3 waves (lane-parallel polls, no RMW anywhere)
    if (w == 0 && l > 0)           waitg(done + ((l - 1) * 2 + rb) * 32, t + 1, lane);
    if (w == 1 && t > 0)           waitg(done + gi * 32, t, lane);
    if (w == 2 && l < 2 && t >= 2) waitg(done + ((l + 1) * 2 + rb) * 32, t - 1, lane);
    __syncthreads();

    const int par = t & 1;
    const short* hprev = hb + (size_t)(1 - par) * HSLOT + (size_t)l * HLAY;

    const short* pH[4];
    const short* pA[4] = {nullptr, nullptr, nullptr, nullptr};
    const float* pXf[4] = {x, x, x, x};
#pragma unroll
    for (int rf = 0; rf < 4; ++rf) {
      int row = R0 + w * 64 + rf * 16 + lrow;
      pH[rf] = hprev + (size_t)row * Hc;
      if (l > 0) {
        pA[rf] = hb + (size_t)par * HSLOT + (size_t)(l - 1) * HLAY + (size_t)row * Hc;
      } else {
        int bb = row >> 6, aa = row & 63;
        size_t rofs = ((size_t)bb * Tc + t) * 64 + aa;
        if (xb) pA[rf] = xb + rofs * Hc;
        pXf[rf] = x + rofs * Hc;
      }
    }

    f32x4 acc[6][4];
#pragma unroll
    for (int m = 0; m < 6; ++m)
#pragma unroll
      for (int rf = 0; rf < 4; ++rf) acc[m][rf] = f32x4{0.f, 0.f, 0.f, 0.f};

#define AI_ISSUE_C(I_, rf, k2, addr) LOADC(I_[rf][k2], addr)
#define AI_ISSUE_N(I_, rf, k2, addr) LOADN(I_[rf][k2], addr)
#define AI_ISSUE_X(I_, rf, k2, addr)
#define AI_GET_REG(dst, I_, rf, k2, ks) dst = I_[rf][k2]
#define AI_GET_F32(dst, I_, rf, k2, ks)                                            \
      {                                                                            \
        const float* _px = pXf[rf] + (ks) * 32 + (kgrp << 3);                      \
        f32x4 v0 = *(const f32x4*)_px;                                             \
        f32x4 v1 = *(const f32x4*)(_px + 4);                                       \
        bf16x8 t_;                                                                 \
        _Pragma("unroll") for (int e = 0; e < 4; ++e) {                            \
          t_[e] = (short)f2bf(v0[e]); t_[4 + e] = (short)f2bf(v1[e]);              \
        }                                                                          \
        dst = t_;                                                                  \
      }

#define ISSUE(H_, I_, g2, AI_ISS)                                                  \
      { _Pragma("unroll") for (int rf = 0; rf < 4; ++rf)                           \
          _Pragma("unroll") for (int k2 = 0; k2 < 2; ++k2) {                       \
            const int ke = ((g2) * 2 + k2) * 32 + (kgrp << 3);                     \
            LOADC(H_[rf][k2], pH[rf] + ke);                                        \
            AI_ISS(I_, rf, k2, pA[rf] + ke);                                       \
          } }

#define CONSUME(H_, I_, g2, AI_GET)                                                \
      { _Pragma("unroll") for (int k2 = 0; k2 < 2; ++k2) {                         \
          const int ks = (g2) * 2 + k2;                                            \
          bf16x8 Bg0 = *(const bf16x8*)(wl + ((0 * 16 + ks) << 10));               \
          bf16x8 Bg1 = *(const bf16x8*)(wl + ((1 * 16 + ks) << 10));               \
          bf16x8 Bg2 = *(const bf16x8*)(wl + ((2 * 16 + ks) << 10));               \
          bf16x8 Bg3 = *(const bf16x8*)(wl + ((3 * 16 + ks) << 10));               \
          bf16x8 Bg4 = *(const bf16x8*)(wl + ((4 * 16 + ks) << 10));               \
          bf16x8 Bg5 = *(const bf16x8*)(wl + ((5 * 16 + ks) << 10));               \
          _Pragma("unroll") for (int rf = 0; rf < 4; ++rf) {                       \
            bf16x8 Ai_; AI_GET(Ai_, I_, rf, k2, ks);                               \
            MM(Ai_, Bg0, acc[0][rf]);                                              \
            MM(Ai_, Bg1, acc[1][rf]);                                              \
            MM(Ai_, Bg2, acc[2][rf]);                                              \
            MM(H_[rf][k2], Bg3, acc[3][rf]);                                       \
            MM(H_[rf][k2], Bg4, acc[4][rf]);                                       \
            MM(H_[rf][k2], Bg5, acc[5][rf]);                                       \
          } } }

#define KLOOP(AI_ISS, AI_GET, WMID)                                                \
      {                                                                            \
        bf16x8 gHa[4][2], gIa[4][2], gHb[4][2], gIb[4][2];                         \
        ISSUE(gHa, gIa, 0, AI_ISS);                                                \
        _Pragma("unroll") for (int g2 = 0; g2 < 8; g2 += 2) {                      \
          ISSUE(gHb, gIb, g2 + 1, AI_ISS);                                         \
          WAITV(WMID);                                                             \
          CONSUME(gHa, gIa, g2, AI_GET);                                           \
          if (g2 + 2 < 8) {                                                        \
            ISSUE(gHa, gIa, g2 + 2, AI_ISS);                                       \
            WAITV(WMID);                                                           \
          } else {                                                                 \
            WAITV(0);                                                              \
          }                                                                        \
          CONSUME(gHb, gIb, g2 + 1, AI_GET);                                       \
        }                                                                          \
      }

    __builtin_amdgcn_sched_barrier(0);
    if (l > 0) {
      KLOOP(AI_ISSUE_C, AI_GET_REG, 16)
    } else if (xb) {
      KLOOP(AI_ISSUE_N, AI_GET_REG, 16)
    } else {                         // fallback: single-buffered, full drains
      bf16x8 gHa[4][2], gIa[4][2];
#pragma unroll
      for (int g2 = 0; g2 < 8; ++g2) {
        ISSUE(gHa, gIa, g2, AI_ISSUE_X);
        WAITV(0);
        CONSUME(gHa, gIa, g2, AI_GET_F32);
      }
    }
    __builtin_amdgcn_sched_barrier(0);

    // epilogue: C/D map col=lane&15, row=(lane>>4)*4+reg (m89-verified)
    short* hout = hb + (size_t)par * HSLOT + (size_t)l * HLAY;
#pragma unroll
    for (int rf = 0; rf < 4; ++rf) {
#pragma unroll
      for (int rr = 0; rr < 4; ++rr) {
        int rowg = R0 + w * 64 + rf * 16 + kgrp * 4 + rr;
        int bb = rowg >> 6, aa = rowg & 63;
        size_t vofs = ((size_t)bb * Tc + t) * 64 + aa;
        int vld = valid[vofs];
        float ir = acc[0][rf][rr] + bi0;
        float iz = acc[1][rf][rr] + bi1;
        float in_ = acc[2][rf][rr] + bi2;
        float hr = acc[3][rf][rr] + bh0;
        float hz = acc[4][rf][rr] + bh1;
        float hn = acc[5][rf][rr] + bh2;
        float rg = 1.0f / (1.0f + __expf(-(ir + hr)));
        float zg = 1.0f / (1.0f + __expf(-(iz + hz)));
        float ng = tanhf(in_ + rg * hn);
        float hnew = (1.0f - zg) * ng + zg * hreg[rf][rr];
        if (!vld) hnew = 0.0f;
        hreg[rf][rr] = hnew;
        int hv = (int)f2bf(hnew);
        STORE_H2(hout + (size_t)rowg * Hc + c, hv);
        if (l == 2) y[vofs * Hc + c] = hnew;
      }
    }

    asm volatile("s_waitcnt vmcnt(0)" ::: "memory");   // per-wave: sc stores at L3
    __syncthreads();                                   // -> ALL waves' stores done
    if (tid == 0) {                  // publish: single sc STORE, no RMW
      int v = t + 1;
      STORE_D(done + gi * 32 + cb, v);
    }
    WAITV(0);   // drain publish store: vmcnt clean for next counted region
  }
}

extern "C" void kernel_launch(void* const* d_in, const int* in_sizes, int n_in,
                              void* d_out, int out_size, void* d_ws, size_t ws_size,
                              hipStream_t stream) {
  const float* x = (const float*)d_in[0];
  const int* valid = (const int*)d_in[1];
  const float* w_ih = (const float*)d_in[2];
  const float* w_hh = (const float*)d_in[3];
  const float* b_ih = (const float*)d_in[4];
  const float* b_hh = (const float*)d_in[5];
  float* y = (float*)d_out;

  char* ws = (char*)d_ws;
  const size_t welems = (size_t)Lc * H3c * Hc;            // 2,359,296
  unsigned short* wbih = (unsigned short*)ws;
  unsigned short* wbhh = (unsigned short*)(ws + welems * 2);
  short* hb = (short*)(ws + welems * 4);                  // 3.0 MB ring
  const size_t hb_bytes = (size_t)2 * HSLOT * 2;
  int* done = (int*)(ws + welems * 4 + hb_bytes);         // [6][32] = 768 B
  const size_t flags_bytes = 4800;
  const size_t xb_off = welems * 4 + hb_bytes + flags_bytes;  // 16B aligned
  const size_t xelems = (size_t)8 * Tc * 64 * Hc;         // 26,214,400
  const bool big = ws_size >= xb_off + xelems * 2;
  unsigned short* xbf = big ? (unsigned short*)(ws + xb_off) : nullptr;

  int n4w = (int)(welems / 4);
  conv_bf16<<<(n4w + 255) / 256, 256, 0, stream>>>(w_ih, wbih, n4w);
  conv_bf16<<<(n4w + 255) / 256, 256, 0, stream>>>(w_hh, wbhh, n4w);
  if (big) {
    int n4x = (int)(xelems / 4);
    conv_bf16<<<(n4x + 255) / 256, 256, 0, stream>>>(x, xbf, n4x);
  }
  (void)hipMemsetAsync(hb, 0, hb_bytes + flags_bytes, stream);

  gru_persist7<<<192, 256, 0, stream>>>(x, (const short*)xbf,
                                        (const short*)wbih, (const short*)wbhh,
                                        b_ih, b_hh, hb, valid, y, done);
}